// Round 16
// baseline (89.265 us; speedup 1.0000x reference)
//
#include <hip/hip_runtime.h>
#include <hip/hip_fp16.h>

// Batched 10-qubit statevector simulator — one 64-lane wave per sample.
// State: 1024 complex amps; s = (r<<6)|lane; qubit q <-> bit (9-q):
//   qubits 0..3 -> register-index bits (16 regs per lane)
//   qubits 4..9 -> lane bits (butterfly exchanges)
// R14: state packed as f16x2 (re,im) in one VGPR — halved DS/DPP traffic
//   (steady ~42 -> ~38.5us) but math gain missing: _Float16 ext-vector ops
//   scalarized to paired v_fma_f16 (4cyc/component == pk_fma_f32 half-rate).
// R15: force TRUE packed math via __half2 + __hfma2/__hmul2 (guaranteed
//   v_pk_fma_f16/v_pk_mul_f16, full-rate 2cyc). Each gate output =
//   1 mul + 3 fma packed ops. Everything else identical to R14.
// Carried: R1/2 lane-parallel coeffs + readlane broadcast; R3 fused ring
//   chain bperm; R5/R10 DPP masks 1,2,8 + 2-DPP mask 4; R9 layer-0 product
//   construction + final ring folded into epilogue parities; fp32
//   coefficients & epilogue accumulation.

constexpr int NQ  = 10;
constexpr int NL  = 5;
constexpr int OBS = 10;

typedef float f2 __attribute__((ext_vector_type(2)));

__device__ __forceinline__ float readlane_f(float v, int l) {
    return __int_as_float(__builtin_amdgcn_readlane(__float_as_int(v), l));
}
__device__ __forceinline__ int h2i(__half2 v) { int i; __builtin_memcpy(&i, &v, 4); return i; }
__device__ __forceinline__ __half2 i2h(int i) { __half2 v; __builtin_memcpy(&v, &i, 4); return v; }

__device__ __forceinline__ __half2 bperm_h2(int byte_addr, __half2 v) {
    return i2h(__builtin_amdgcn_ds_bpermute(byte_addr, h2i(v)));
}
template <int CTRL>
__device__ __forceinline__ __half2 dpp_h2(__half2 v) {
    return i2h(__builtin_amdgcn_update_dpp(0, h2i(v), CTRL, 0xF, 0xF, true));
}
// xor-exchange across lanes; M compile-time -> branches fold.
__device__ __forceinline__ __half2 xor_lane(__half2 v, int M, int a16, int a32) {
    switch (M) {
    case 1:  return dpp_h2<0xB1>(v);                // quad_perm [1,0,3,2]
    case 2:  return dpp_h2<0x4E>(v);                // quad_perm [2,3,0,1]
    case 8:  return dpp_h2<0x128>(v);               // row_ror:8 == lane^8
    case 4:  return dpp_h2<0x141>(dpp_h2<0x1B>(v)); // xor3 ∘ xor7 = xor4
    case 16: return bperm_h2(a16, v);
    default: return bperm_h2(a32, v);               // 32
    }
}
__device__ __forceinline__ __half2 swap_h2(__half2 v) { return __lowhigh2highlow(v); }
// 4-term packed complex-pair accumulation: a*b + c*d + e*f + g*h
__device__ __forceinline__ __half2 acc4(__half2 a, __half2 b, __half2 c, __half2 d,
                                        __half2 e, __half2 f, __half2 g, __half2 h) {
    return __hfma2(a, b, __hfma2(c, d, __hfma2(e, f, __hmul2(g, h))));
}

__global__ __launch_bounds__(256, 4) void qsim_kernel(
    const float* __restrict__ x,       // (B, 10)
    const float* __restrict__ isc,     // (5, 20)
    const float* __restrict__ w,       // (5, 20)
    const float* __restrict__ oscale,  // (4)
    float* __restrict__ out,           // (B, 4)
    int B)
{
    const int lane = threadIdx.x & 63;
    const int wid  = (blockIdx.x * blockDim.x + threadIdx.x) >> 6;
    if (wid >= B) return;

    // ---- lane-parallel gate-coefficient computation (gates 0..49), fp32 ----
    float cUR, cUI, cVR, cVI;
    {
        const int g   = (lane < 50) ? lane : 49;
        const int q   = g % 10;
        const int lyr = g / 10;
        const float xq    = x[wid * OBS + q];
        const float alpha = isc[lyr * 2 * NQ + q]      * xq;
        const float beta  = isc[lyr * 2 * NQ + NQ + q] * xq;
        const float gamma = w[lyr * 2 * NQ + q];
        const float delta = w[lyr * 2 * NQ + NQ + q];
        float sa, ca, sp, cp, sd, cd;
        __sincosf(0.5f * alpha,          &sa, &ca);
        __sincosf(0.5f * (beta + gamma), &sp, &cp);
        __sincosf(0.5f * delta,          &sd, &cd);
        const float A = cd * ca, Bt = sd * sa;
        const float C = cd * sa, D  = sd * ca;
        cUR = (A - Bt) * cp;
        cUI = -(A + Bt) * sp;
        cVR = (C + D) * cp;
        cVI = (C - D) * sp;
    }

    // hoisted bpermute byte-addresses (loop-invariant)
    const int a16 = (lane ^ 16) * 4;
    const int a32 = (lane ^ 32) * 4;
    const int cnot_src  = (lane ^ (lane >> 1));
    const int addr_even = cnot_src * 4;            // r bit0 == 0
    const int addr_odd  = (cnot_src ^ 32) * 4;     // r bit0 == 1 (CNOT(3,4))

    __half2 c[16];

    // ===== layer 0: direct product-state construction (fp32 -> f16x2) =====
    // amp(s) = prod_q (bit_q(s) ? v_q : u_q), gate column (u,v)=U|0>.
    {
        float Lr = 1.f, Li = 0.f;
#pragma unroll
        for (int q = 4; q < 10; ++q) {
            const float ur = readlane_f(cUR, q), ui = readlane_f(cUI, q);
            const float vr = readlane_f(cVR, q), vi = readlane_f(cVI, q);
            const int M = 1 << (9 - q);
            const float fr = (lane & M) ? vr : ur;
            const float fi = (lane & M) ? vi : ui;
            const float nr = Lr * fr - Li * fi;
            const float ni = Lr * fi + Li * fr;
            Lr = nr; Li = ni;
        }
        f2 cf[16];
        cf[0] = (f2){Lr, Li};
#pragma unroll
        for (int r = 1; r < 16; ++r) cf[r] = (f2){0.f, 0.f};
#pragma unroll
        for (int q = 3; q >= 0; --q) {
            const int m = 1 << (3 - q);
            const float ur = readlane_f(cUR, q), ui = readlane_f(cUI, q);
            const float vr = readlane_f(cVR, q), vi = readlane_f(cVI, q);
#pragma unroll
            for (int r0 = 0; r0 < 16; ++r0) {
                if (r0 >= m) continue;
                const f2 s = cf[r0];
                cf[r0 | m] = (f2){ s.x*vr - s.y*vi, s.x*vi + s.y*vr };
                cf[r0]     = (f2){ s.x*ur - s.y*ui, s.x*ui + s.y*ur };
            }
        }
#pragma unroll
        for (int r = 0; r < 16; ++r) c[r] = __floats2half2_rn(cf[r].x, cf[r].y);
    }

#define SWAPR(i, j) { __half2 _t = c[i]; c[i] = c[j]; c[j] = _t; }

    for (int layer = 0; layer < NL; ++layer) {
        const int base = layer * NQ;   // wave-uniform

        // ---- fused single-qubit unitaries (layer 0 done by construction) ----
        if (layer > 0) {
#pragma unroll
            for (int q = 0; q < NQ; ++q) {
                const float ur = readlane_f(cUR, base + q);
                const float ui = readlane_f(cUI, base + q);
                const float vr = readlane_f(cVR, base + q);
                const float vi = readlane_f(cVI, base + q);

                if (q < 4) {
                    // register-bit qubit: pair stride m inside the lane.
                    const __half2 kUU  = __floats2half2_rn(ur, ur);
                    const __half2 kUIm = __floats2half2_rn(-ui, ui);
                    const __half2 kVVn = __floats2half2_rn(-vr, -vr);
                    const __half2 kVV  = __floats2half2_rn(vr, vr);
                    const __half2 kVIm = __floats2half2_rn(-vi, vi);
                    const __half2 kUIp = __floats2half2_rn(ui, -ui);
                    const int m = 1 << (3 - q);
#pragma unroll
                    for (int r0 = 0; r0 < 16; ++r0) {
                        if (r0 & m) continue;
                        const int r1 = r0 | m;
                        const __half2 c0 = c[r0], c1 = c[r1];
                        const __half2 c0s = swap_h2(c0), c1s = swap_h2(c1);
                        c[r0] = acc4(kUU, c0, kUIm, c0s, kVVn, c1, kVIm, c1s);
                        c[r1] = acc4(kVV, c0, kVIm, c0s, kUU,  c1, kUIp, c1s);
                    }
                } else {
                    // lane-bit qubit: butterfly exchange with lane^M.
                    const int  M   = 1 << (9 - q);
                    const bool bit = (lane & M) != 0;
                    const float Pi = bit ? -ui : ui;
                    const float Qr = bit ?  vr : -vr;
                    const __half2 kUUb = __floats2half2_rn(ur, ur);
                    const __half2 kPI  = __floats2half2_rn(-Pi, Pi);
                    const __half2 kQR  = __floats2half2_rn(Qr, Qr);
                    const __half2 kVIb = __floats2half2_rn(-vi, vi);
#pragma unroll
                    for (int r = 0; r < 16; ++r) {
                        const __half2 mv = c[r];
                        const __half2 pv = xor_lane(mv, M, a16, a32);
                        c[r] = acc4(kUUb, mv, kPI, swap_h2(mv), kQR, pv, kVIb, swap_h2(pv));
                    }
                }
            }
        }

        // ---- CNOT ring (skipped on last layer; folded into epilogue) ----
        if (layer < NL - 1) {
            // CNOT(0,1): ctrl r-bit3, tgt r-bit2 -> register swap
            SWAPR(8, 12) SWAPR(9, 13) SWAPR(10, 14) SWAPR(11, 15)
            // CNOT(1,2): ctrl r-bit2, tgt r-bit1
            SWAPR(4, 6)  SWAPR(5, 7)  SWAPR(12, 14) SWAPR(13, 15)
            // CNOT(2,3): ctrl r-bit1, tgt r-bit0
            SWAPR(2, 3)  SWAPR(6, 7)  SWAPR(10, 11) SWAPR(14, 15)
            // CNOT(3,4)..(8,9) fused: ONE bpermute per amplitude (f16x2).
#pragma unroll
            for (int r = 0; r < 16; ++r) {
                const int addr = (r & 1) ? addr_odd : addr_even;
                c[r] = bperm_h2(addr, c[r]);
            }
            // CNOT(9,0): ctrl lane-bit0, tgt r-bit3 -> cond register swap
            const bool ctl = (lane & 1) != 0;
#pragma unroll
            for (int r = 0; r < 8; ++r) {
                const __half2 t0 = c[r], t1 = c[r + 8];
                c[r]     = ctl ? t1 : t0;
                c[r + 8] = ctl ? t0 : t1;
            }
        }
    }

    // ---- epilogue (fp32): <Z_i> after the (virtual) final ring ----
    // (Cb)_0 = q1+..+q9 -> reg bits r2,r1,r0 + all 6 lane bits
    // (Cb)_1 = q0+q1 -> r3,r2 ; (Cb)_2 -> r3,r2,r1 ; (Cb)_3 -> r3..r0
    const float sL = (__popc(lane) & 1) ? -1.f : 1.f;
    float z0 = 0.f, z1 = 0.f, z2 = 0.f, z3 = 0.f;
#pragma unroll
    for (int r = 0; r < 16; ++r) {
        const float cr = __low2float(c[r]), ci = __high2float(c[r]);
        const float pv  = cr * cr + ci * ci;
        const float pvl = sL * pv;
        z0 += (__popc(r & 7)  & 1) ? -pvl : pvl;
        z1 += (__popc(r & 12) & 1) ? -pv  : pv;
        z2 += (__popc(r & 14) & 1) ? -pv  : pv;
        z3 += (__popc(r & 15) & 1) ? -pv  : pv;
    }
    // f32 xor-lane reduction (DPP for 1,2,4,8; bperm for 16,32)
    {
        auto dpp_f32 = [](float v, int ctrl) -> float {
            switch (ctrl) {
            case 0xB1:  return __int_as_float(__builtin_amdgcn_update_dpp(0, __float_as_int(v), 0xB1, 0xF, 0xF, true));
            case 0x4E:  return __int_as_float(__builtin_amdgcn_update_dpp(0, __float_as_int(v), 0x4E, 0xF, 0xF, true));
            case 0x128: return __int_as_float(__builtin_amdgcn_update_dpp(0, __float_as_int(v), 0x128, 0xF, 0xF, true));
            default:    return __int_as_float(__builtin_amdgcn_update_dpp(0,
                               __builtin_amdgcn_update_dpp(0, __float_as_int(v), 0x1B, 0xF, 0xF, true),
                               0x141, 0xF, 0xF, true));   // xor4
            }
        };
        z0 += dpp_f32(z0, 0xB1);  z1 += dpp_f32(z1, 0xB1);
        z2 += dpp_f32(z2, 0xB1);  z3 += dpp_f32(z3, 0xB1);
        z0 += dpp_f32(z0, 0x4E);  z1 += dpp_f32(z1, 0x4E);
        z2 += dpp_f32(z2, 0x4E);  z3 += dpp_f32(z3, 0x4E);
        z0 += dpp_f32(z0, 0);     z1 += dpp_f32(z1, 0);
        z2 += dpp_f32(z2, 0);     z3 += dpp_f32(z3, 0);
        z0 += dpp_f32(z0, 0x128); z1 += dpp_f32(z1, 0x128);
        z2 += dpp_f32(z2, 0x128); z3 += dpp_f32(z3, 0x128);
        z0 += __int_as_float(__builtin_amdgcn_ds_bpermute(a16, __float_as_int(z0)));
        z1 += __int_as_float(__builtin_amdgcn_ds_bpermute(a16, __float_as_int(z1)));
        z2 += __int_as_float(__builtin_amdgcn_ds_bpermute(a16, __float_as_int(z2)));
        z3 += __int_as_float(__builtin_amdgcn_ds_bpermute(a16, __float_as_int(z3)));
        z0 += __int_as_float(__builtin_amdgcn_ds_bpermute(a32, __float_as_int(z0)));
        z1 += __int_as_float(__builtin_amdgcn_ds_bpermute(a32, __float_as_int(z1)));
        z2 += __int_as_float(__builtin_amdgcn_ds_bpermute(a32, __float_as_int(z2)));
        z3 += __int_as_float(__builtin_amdgcn_ds_bpermute(a32, __float_as_int(z3)));
    }
    if (lane == 0) {
        out[wid * 4 + 0] = z0 * oscale[0];
        out[wid * 4 + 1] = z1 * oscale[1];
        out[wid * 4 + 2] = z2 * oscale[2];
        out[wid * 4 + 3] = z3 * oscale[3];
    }
#undef SWAPR
}

extern "C" void kernel_launch(void* const* d_in, const int* in_sizes, int n_in,
                              void* d_out, int out_size, void* d_ws, size_t ws_size,
                              hipStream_t stream) {
    const float* x      = (const float*)d_in[0];
    const float* isc    = (const float*)d_in[1];
    const float* w      = (const float*)d_in[2];
    const float* oscale = (const float*)d_in[3];
    float* out = (float*)d_out;

    const int B = in_sizes[0] / OBS;             // 4096
    const int threads = 256;                     // 4 waves -> 4 samples per block
    const int blocks = (B * 64 + threads - 1) / threads;
    qsim_kernel<<<blocks, threads, 0, stream>>>(x, isc, w, oscale, out, B);
}